// Round 1
// baseline (2738.809 us; speedup 1.0000x reference)
//
#include <hip/hip_runtime.h>
#include <math.h>

#define D_MODEL 1024
#define NH 16
#define HD 64
#define SEQ 2048
#define NB 2
#define BSROWS (NB * SEQ)   // 4096

// ---------------------------------------------------------------------------
// NT-GEMM: C[i,o] = sum_k A[i,k] * W[o,k] + bias[o]
//   A: [M=4096, K=1024] row-major, W: [N=1024, K=1024] row-major (torch Linear)
// SPLITHEAD=1: store into [B, H, S, hd] layout (for Q/K/V)
// SPLITHEAD=0: store into [M, N] flat (attn-out merge / final output)
// Tile: 64x64, BK=32, 256 threads, 4x4 per-thread microtile.
// ---------------------------------------------------------------------------
template <int SPLITHEAD>
__global__ __launch_bounds__(256) void gemm_nt(const float* __restrict__ A,
                                               const float* __restrict__ W,
                                               const float* __restrict__ bias,
                                               float* __restrict__ out) {
    __shared__ float As[64][33];   // pad +1: inner-loop reads are <=2-way (free)
    __shared__ float Ws[64][33];

    const int tid = threadIdx.x;
    const int i0  = blockIdx.x * 64;   // row tile base (tokens)
    const int o0  = blockIdx.y * 64;   // col tile base (out features)
    const int ty  = tid >> 4;          // 0..15
    const int tx  = tid & 15;          // 0..15
    const int lr  = tid >> 3;          // 0..31  (staging row)
    const int lc  = (tid & 7) << 2;    // 0..28  (staging col, float4)

    float acc[4][4] = {};

    for (int k0 = 0; k0 < D_MODEL; k0 += 32) {
        // coalesced float4 global loads (each thread: 2 rows of A, 2 rows of W)
        const float4 a0 = *(const float4*)&A[(size_t)(i0 + lr)      * D_MODEL + k0 + lc];
        const float4 a1 = *(const float4*)&A[(size_t)(i0 + lr + 32) * D_MODEL + k0 + lc];
        const float4 w0 = *(const float4*)&W[(size_t)(o0 + lr)      * D_MODEL + k0 + lc];
        const float4 w1 = *(const float4*)&W[(size_t)(o0 + lr + 32) * D_MODEL + k0 + lc];

        __syncthreads();   // previous tile fully consumed
        As[lr][lc + 0] = a0.x; As[lr][lc + 1] = a0.y; As[lr][lc + 2] = a0.z; As[lr][lc + 3] = a0.w;
        As[lr + 32][lc + 0] = a1.x; As[lr + 32][lc + 1] = a1.y; As[lr + 32][lc + 2] = a1.z; As[lr + 32][lc + 3] = a1.w;
        Ws[lr][lc + 0] = w0.x; Ws[lr][lc + 1] = w0.y; Ws[lr][lc + 2] = w0.z; Ws[lr][lc + 3] = w0.w;
        Ws[lr + 32][lc + 0] = w1.x; Ws[lr + 32][lc + 1] = w1.y; Ws[lr + 32][lc + 2] = w1.z; Ws[lr + 32][lc + 3] = w1.w;
        __syncthreads();

#pragma unroll
        for (int kk = 0; kk < 32; ++kk) {
            float av[4], wv[4];
#pragma unroll
            for (int i = 0; i < 4; ++i) av[i] = As[ty * 4 + i][kk];
#pragma unroll
            for (int j = 0; j < 4; ++j) wv[j] = Ws[tx * 4 + j][kk];
#pragma unroll
            for (int i = 0; i < 4; ++i)
#pragma unroll
                for (int j = 0; j < 4; ++j) acc[i][j] += av[i] * wv[j];
        }
    }

    const int col0 = o0 + tx * 4;
#pragma unroll
    for (int i = 0; i < 4; ++i) {
        const int row = i0 + ty * 4 + i;
        float4 r;
        r.x = acc[i][0] + bias[col0 + 0];
        r.y = acc[i][1] + bias[col0 + 1];
        r.z = acc[i][2] + bias[col0 + 2];
        r.w = acc[i][3] + bias[col0 + 3];
        if (SPLITHEAD) {
            const int bb = row >> 11;          // row / SEQ
            const int s  = row & (SEQ - 1);
            const int h  = col0 >> 6;
            const int d  = col0 & 63;          // col0 is 4-aligned, stays in-head
            *(float4*)&out[(((size_t)bb * NH + h) * SEQ + s) * HD + d] = r;
        } else {
            *(float4*)&out[(size_t)row * D_MODEL + col0] = r;
        }
    }
}

// ---------------------------------------------------------------------------
// Flash-style attention, fp32. One 64-lane wave per block; lane = 1 query row.
// Q,K,V in [B,H,S,hd]. Output written merged [B,S,D] (row-major [4096][1024]).
// ---------------------------------------------------------------------------
__global__ __launch_bounds__(64) void attn_kernel(const float* __restrict__ Q,
                                                  const float* __restrict__ K,
                                                  const float* __restrict__ V,
                                                  float* __restrict__ Aout) {
    __shared__ float Ks[64][HD];
    __shared__ float Vs[64][HD];

    const int tid = threadIdx.x;           // 0..63 -> query row within tile
    const int qt  = blockIdx.x;            // query tile
    const int h   = blockIdx.y;
    const int b   = blockIdx.z;
    const size_t headoff = ((size_t)b * NH + h) * SEQ * HD;

    const float* Qrow = Q + headoff + (size_t)(qt * 64 + tid) * HD;
    float q[HD];
#pragma unroll
    for (int d = 0; d < HD; d += 4) {
        const float4 t = *(const float4*)&Qrow[d];
        q[d] = t.x; q[d + 1] = t.y; q[d + 2] = t.z; q[d + 3] = t.w;
    }

    float acc[HD] = {};
    float m = -INFINITY, l = 0.f;
    const float scale = 0.125f;            // 1/sqrt(64)

    const int lrow = tid >> 4;             // 0..3
    const int lcol = (tid & 15) << 2;      // 0..60

    for (int kt = 0; kt < SEQ / 64; ++kt) {
        const float* Kt = K + headoff + (size_t)kt * 64 * HD;
        const float* Vt = V + headoff + (size_t)kt * 64 * HD;
        __syncthreads();                   // previous tile consumed
#pragma unroll
        for (int r = 0; r < 16; ++r) {
            const int row = r * 4 + lrow;  // coalesced: wave covers 4 rows x 256B
            *(float4*)&Ks[row][lcol] = *(const float4*)&Kt[row * HD + lcol];
            *(float4*)&Vs[row][lcol] = *(const float4*)&Vt[row * HD + lcol];
        }
        __syncthreads();

        for (int jc = 0; jc < 64; jc += 16) {   // 16-wide chunks: s[] register-resident
            float s[16];
            float tmax = m;
#pragma unroll
            for (int jj = 0; jj < 16; ++jj) {
                float sum = 0.f;
#pragma unroll
                for (int k = 0; k < HD; k += 4) {   // broadcast b128 reads: conflict-free
                    const float4 kv = *(const float4*)&Ks[jc + jj][k];
                    sum += q[k] * kv.x + q[k + 1] * kv.y + q[k + 2] * kv.z + q[k + 3] * kv.w;
                }
                s[jj] = sum * scale;
                tmax = fmaxf(tmax, s[jj]);
            }
            const float corr = __expf(m - tmax);
            m = tmax;
            l *= corr;
#pragma unroll
            for (int d = 0; d < HD; ++d) acc[d] *= corr;
#pragma unroll
            for (int jj = 0; jj < 16; ++jj) {
                const float p = __expf(s[jj] - m);
                l += p;
#pragma unroll
                for (int d = 0; d < HD; d += 4) {
                    const float4 vv = *(const float4*)&Vs[jc + jj][d];
                    acc[d]     += p * vv.x;
                    acc[d + 1] += p * vv.y;
                    acc[d + 2] += p * vv.z;
                    acc[d + 3] += p * vv.w;
                }
            }
        }
    }

    const float inv = 1.f / l;
    float* orow = Aout + (size_t)(b * SEQ + qt * 64 + tid) * D_MODEL + h * HD;
#pragma unroll
    for (int d = 0; d < HD; d += 4) {
        float4 r;
        r.x = acc[d] * inv; r.y = acc[d + 1] * inv;
        r.z = acc[d + 2] * inv; r.w = acc[d + 3] * inv;
        *(float4*)&orow[d] = r;
    }
}

// ---------------------------------------------------------------------------
extern "C" void kernel_launch(void* const* d_in, const int* in_sizes, int n_in,
                              void* d_out, int out_size, void* d_ws, size_t ws_size,
                              hipStream_t stream) {
    const float* x  = (const float*)d_in[0];
    const float* Wq = (const float*)d_in[1];
    const float* bq = (const float*)d_in[2];
    const float* Wk = (const float*)d_in[3];
    const float* bk = (const float*)d_in[4];
    const float* Wv = (const float*)d_in[5];
    const float* bv = (const float*)d_in[6];
    const float* Wo = (const float*)d_in[7];
    const float* bo = (const float*)d_in[8];
    float* out = (float*)d_out;

    // workspace layout: Q | K | V in [B,H,S,hd]; Aw merged [B*S, D]
    float* Qw = (float*)d_ws;
    float* Kw = Qw + (size_t)BSROWS * D_MODEL;
    float* Vw = Kw + (size_t)BSROWS * D_MODEL;
    float* Aw = Vw + (size_t)BSROWS * D_MODEL;
    // requires ws_size >= 4 * 4096 * 1024 * 4B = 64 MiB

    const dim3 gg(BSROWS / 64, D_MODEL / 64);   // (64, 16)
    gemm_nt<1><<<gg, 256, 0, stream>>>(x, Wq, bq, Qw);
    gemm_nt<1><<<gg, 256, 0, stream>>>(x, Wk, bk, Kw);
    gemm_nt<1><<<gg, 256, 0, stream>>>(x, Wv, bv, Vw);

    attn_kernel<<<dim3(SEQ / 64, NH, NB), 64, 0, stream>>>(Qw, Kw, Vw, Aw);

    gemm_nt<0><<<gg, 256, 0, stream>>>(Aw, Wo, bo, out);
}

// Round 3
// 788.809 us; speedup vs baseline: 3.4721x; 3.4721x over previous
//
#include <hip/hip_runtime.h>
#include <math.h>

#define D_MODEL 1024
#define NH 16
#define HD 64
#define SEQ 2048
#define NB 2
#define BSROWS (NB * SEQ)   // 4096

typedef __attribute__((ext_vector_type(8))) short short8;
typedef __attribute__((ext_vector_type(4))) float f32x4;

__device__ __forceinline__ ushort bf16rne(float f) {
    union { float f; uint32_t u; } v; v.f = f;
    return (ushort)((v.u + 0x7FFFu + ((v.u >> 16) & 1u)) >> 16);
}

// ---------------------------------------------------------------------------
// NT-GEMM: C[i,o] = (sum_k A[i,k] * W[o,k] + bias[o]) * scale
// MODE 0: fp32 out, flat [M][N]
// MODE 1: bf16 out, split-head [B,H,S,hd]          (Q with scale=0.125, K)
// MODE 2: bf16 out, transposed split-head [B,H,hd,S] (V)
// ---------------------------------------------------------------------------
template <int MODE>
__global__ __launch_bounds__(256) void gemm_nt(const float* __restrict__ A,
                                               const float* __restrict__ W,
                                               const float* __restrict__ bias,
                                               void* __restrict__ outv,
                                               float scale) {
    __shared__ float As[64][33];
    __shared__ float Ws[64][33];

    const int tid = threadIdx.x;
    const int i0  = blockIdx.x * 64;
    const int o0  = blockIdx.y * 64;
    const int ty  = tid >> 4;
    const int tx  = tid & 15;
    const int lr  = tid >> 3;
    const int lc  = (tid & 7) << 2;

    float acc[4][4] = {};

    for (int k0 = 0; k0 < D_MODEL; k0 += 32) {
        const float4 a0 = *(const float4*)&A[(size_t)(i0 + lr)      * D_MODEL + k0 + lc];
        const float4 a1 = *(const float4*)&A[(size_t)(i0 + lr + 32) * D_MODEL + k0 + lc];
        const float4 w0 = *(const float4*)&W[(size_t)(o0 + lr)      * D_MODEL + k0 + lc];
        const float4 w1 = *(const float4*)&W[(size_t)(o0 + lr + 32) * D_MODEL + k0 + lc];

        __syncthreads();
        As[lr][lc + 0] = a0.x; As[lr][lc + 1] = a0.y; As[lr][lc + 2] = a0.z; As[lr][lc + 3] = a0.w;
        As[lr + 32][lc + 0] = a1.x; As[lr + 32][lc + 1] = a1.y; As[lr + 32][lc + 2] = a1.z; As[lr + 32][lc + 3] = a1.w;
        Ws[lr][lc + 0] = w0.x; Ws[lr][lc + 1] = w0.y; Ws[lr][lc + 2] = w0.z; Ws[lr][lc + 3] = w0.w;
        Ws[lr + 32][lc + 0] = w1.x; Ws[lr + 32][lc + 1] = w1.y; Ws[lr + 32][lc + 2] = w1.z; Ws[lr + 32][lc + 3] = w1.w;
        __syncthreads();

#pragma unroll
        for (int kk = 0; kk < 32; ++kk) {
            float av[4], wv[4];
#pragma unroll
            for (int i = 0; i < 4; ++i) av[i] = As[ty * 4 + i][kk];
#pragma unroll
            for (int j = 0; j < 4; ++j) wv[j] = Ws[tx * 4 + j][kk];
#pragma unroll
            for (int i = 0; i < 4; ++i)
#pragma unroll
                for (int j = 0; j < 4; ++j) acc[i][j] += av[i] * wv[j];
        }
    }

    const int col0 = o0 + tx * 4;
    const int row0 = i0 + ty * 4;
    const int bb   = row0 >> 11;            // row / SEQ (rows 0..3 same batch)
    const int s0   = row0 & (SEQ - 1);

    if (MODE == 0) {
        float* out = (float*)outv;
#pragma unroll
        for (int i = 0; i < 4; ++i) {
            float4 r;
            r.x = acc[i][0] + bias[col0 + 0];
            r.y = acc[i][1] + bias[col0 + 1];
            r.z = acc[i][2] + bias[col0 + 2];
            r.w = acc[i][3] + bias[col0 + 3];
            *(float4*)&out[(size_t)(row0 + i) * D_MODEL + col0] = r;
        }
    } else if (MODE == 1) {
        ushort* out = (ushort*)outv;
        const int h = col0 >> 6;
        const int d = col0 & 63;
#pragma unroll
        for (int i = 0; i < 4; ++i) {
            ushort4 r;
            r.x = bf16rne((acc[i][0] + bias[col0 + 0]) * scale);
            r.y = bf16rne((acc[i][1] + bias[col0 + 1]) * scale);
            r.z = bf16rne((acc[i][2] + bias[col0 + 2]) * scale);
            r.w = bf16rne((acc[i][3] + bias[col0 + 3]) * scale);
            *(ushort4*)&out[(((size_t)bb * NH + h) * SEQ + (s0 + i)) * HD + d] = r;
        }
    } else {
        ushort* out = (ushort*)outv;
        const int h = col0 >> 6;
        const int d = col0 & 63;
#pragma unroll
        for (int j = 0; j < 4; ++j) {       // fixed feature, 4 consecutive tokens
            const float bj = bias[col0 + j];
            ushort4 r;
            r.x = bf16rne(acc[0][j] + bj);
            r.y = bf16rne(acc[1][j] + bj);
            r.z = bf16rne(acc[2][j] + bj);
            r.w = bf16rne(acc[3][j] + bj);
            *(ushort4*)&out[(((size_t)bb * NH + h) * HD + (d + j)) * SEQ + s0] = r;
        }
    }
}

// ---------------------------------------------------------------------------
// MFMA flash attention. 4 waves/block, 64 q-rows/block (16 per wave), KV tiles
// of 64. Q pre-scaled by 1/sqrt(hd). Q/K: bf16 [B,H,S,hd]; V: bf16 [B,H,hd,S].
// Output: fp32 merged [B*S, D_MODEL].
// All LDS tiles XOR-swizzled: elem col ^= (row&7)<<3  (= byte ^ (row&7)<<4).
// ---------------------------------------------------------------------------
__global__ __launch_bounds__(256) void attn_mfma(const ushort* __restrict__ Q,
                                                 const ushort* __restrict__ K,
                                                 const ushort* __restrict__ Vt,
                                                 float* __restrict__ Aout) {
    __shared__ ushort Qs[64 * 64];
    __shared__ ushort Ks[64 * 64];
    __shared__ ushort Vts[64 * 64];
    __shared__ ushort Ps[4 * 16 * 64];

    const int tid = threadIdx.x;
    const int w   = tid >> 6;       // wave 0..3
    const int l   = tid & 63;
    const int qt  = blockIdx.x;
    const int h   = blockIdx.y;
    const int b   = blockIdx.z;
    const size_t bh = (size_t)b * NH + h;

    const ushort* Qg = Q  + (bh * SEQ + (size_t)qt * 64) * HD;
    const ushort* Kg = K  + bh * SEQ * HD;
    const ushort* Vg = Vt + bh * HD * SEQ;

    // stage Q once: 64 rows x 8 chunks of 8 bf16
    for (int g = tid; g < 512; g += 256) {
        const int row = g >> 3, c = g & 7;
        uint4 v = *(const uint4*)&Qg[row * HD + c * 8];
        *(uint4*)&Qs[row * 64 + ((c * 8) ^ ((row & 7) << 3))] = v;
    }

    const int g16  = l >> 4;        // 0..3
    const int c16  = l & 15;
    const int kcol = g16 * 8;       // fragment k-chunk within 32

    f32x4 o_acc[4];
#pragma unroll
    for (int dd = 0; dd < 4; ++dd) o_acc[dd] = (f32x4){0.f, 0.f, 0.f, 0.f};
    float m[4], lsum[4];
#pragma unroll
    for (int r = 0; r < 4; ++r) { m[r] = -INFINITY; lsum[r] = 0.f; }

    for (int kt = 0; kt < SEQ / 64; ++kt) {
        __syncthreads();
        const ushort* Kt = Kg + (size_t)kt * 64 * HD;
        for (int g = tid; g < 512; g += 256) {
            const int row = g >> 3, c = g & 7;
            uint4 v = *(const uint4*)&Kt[row * HD + c * 8];
            *(uint4*)&Ks[row * 64 + ((c * 8) ^ ((row & 7) << 3))] = v;
        }
        for (int g = tid; g < 512; g += 256) {
            const int row = g >> 3, c = g & 7;   // row = d
            uint4 v = *(const uint4*)&Vg[(size_t)row * SEQ + kt * 64 + c * 8];
            *(uint4*)&Vts[row * 64 + ((c * 8) ^ ((row & 7) << 3))] = v;
        }
        __syncthreads();

        // ---- QK^T: 16q x 64t per wave ----
        f32x4 s[4];
#pragma unroll
        for (int tt = 0; tt < 4; ++tt) s[tt] = (f32x4){0.f, 0.f, 0.f, 0.f};
#pragma unroll
        for (int kc = 0; kc < 2; ++kc) {
            const int qrow = w * 16 + c16;
            const short8 aq = *(const short8*)&Qs[qrow * 64 + ((kc * 32 + kcol) ^ ((qrow & 7) << 3))];
#pragma unroll
            for (int tt = 0; tt < 4; ++tt) {
                const int krow = tt * 16 + c16;
                const short8 bk = *(const short8*)&Ks[krow * 64 + ((kc * 32 + kcol) ^ ((krow & 7) << 3))];
                s[tt] = __builtin_amdgcn_mfma_f32_16x16x32_bf16(aq, bk, s[tt], 0, 0, 0);
            }
        }

        // ---- online softmax (rows q = g16*4+r, spread over 16 lanes c16) ----
        float cm[4];
#pragma unroll
        for (int r = 0; r < 4; ++r)
            cm[r] = fmaxf(fmaxf(s[0][r], s[1][r]), fmaxf(s[2][r], s[3][r]));
#pragma unroll
        for (int off = 8; off >= 1; off >>= 1)
#pragma unroll
            for (int r = 0; r < 4; ++r) cm[r] = fmaxf(cm[r], __shfl_xor(cm[r], off));

        float corr[4];
#pragma unroll
        for (int r = 0; r < 4; ++r) {
            const float mn = fmaxf(m[r], cm[r]);
            corr[r] = __expf(m[r] - mn);
            m[r] = mn;
        }
        float ps[4] = {0.f, 0.f, 0.f, 0.f};
#pragma unroll
        for (int tt = 0; tt < 4; ++tt)
#pragma unroll
            for (int r = 0; r < 4; ++r) {
                const float p = __expf(s[tt][r] - m[r]);
                s[tt][r] = p;
                ps[r] += p;
            }
#pragma unroll
        for (int off = 8; off >= 1; off >>= 1)
#pragma unroll
            for (int r = 0; r < 4; ++r) ps[r] += __shfl_xor(ps[r], off);
#pragma unroll
        for (int r = 0; r < 4; ++r) lsum[r] = lsum[r] * corr[r] + ps[r];
#pragma unroll
        for (int dd = 0; dd < 4; ++dd)
#pragma unroll
            for (int r = 0; r < 4; ++r) o_acc[dd][r] *= corr[r];

        // ---- P -> LDS (bf16, transpose to A-fragment layout) ----
#pragma unroll
        for (int tt = 0; tt < 4; ++tt)
#pragma unroll
            for (int r = 0; r < 4; ++r) {
                const int q = g16 * 4 + r;
                const int t = c16 + tt * 16;
                Ps[w * 1024 + q * 64 + (t ^ ((q & 7) << 3))] = bf16rne(s[tt][r]);
            }

        // ---- PV: out[16q][64d] += P[16q][64t] * Vt[64d][64t]^T ----
#pragma unroll
        for (int kc = 0; kc < 2; ++kc) {
            const int prow = c16;
            const short8 ap = *(const short8*)&Ps[w * 1024 + prow * 64 + ((kc * 32 + kcol) ^ ((prow & 7) << 3))];
#pragma unroll
            for (int dd = 0; dd < 4; ++dd) {
                const int vrow = dd * 16 + c16;
                const short8 bv = *(const short8*)&Vts[vrow * 64 + ((kc * 32 + kcol) ^ ((vrow & 7) << 3))];
                o_acc[dd] = __builtin_amdgcn_mfma_f32_16x16x32_bf16(ap, bv, o_acc[dd], 0, 0, 0);
            }
        }
    }

    // ---- epilogue: normalize, write merged [B*S, D] fp32 ----
#pragma unroll
    for (int r = 0; r < 4; ++r) {
        const float inv = 1.f / lsum[r];
        const size_t row = (size_t)b * SEQ + qt * 64 + w * 16 + g16 * 4 + r;
#pragma unroll
        for (int dd = 0; dd < 4; ++dd)
            Aout[row * D_MODEL + h * HD + c16 + dd * 16] = o_acc[dd][r] * inv;
    }
}

// ---------------------------------------------------------------------------
extern "C" void kernel_launch(void* const* d_in, const int* in_sizes, int n_in,
                              void* d_out, int out_size, void* d_ws, size_t ws_size,
                              hipStream_t stream) {
    const float* x  = (const float*)d_in[0];
    const float* Wq = (const float*)d_in[1];
    const float* bq = (const float*)d_in[2];
    const float* Wk = (const float*)d_in[3];
    const float* bk = (const float*)d_in[4];
    const float* Wv = (const float*)d_in[5];
    const float* bv = (const float*)d_in[6];
    const float* Wo = (const float*)d_in[7];
    const float* bo = (const float*)d_in[8];
    float* out = (float*)d_out;

    // ws: Q,K bf16 [B,H,S,hd]; V bf16 [B,H,hd,S]; Aw fp32 [B*S, D]
    ushort* Qw = (ushort*)d_ws;
    ushort* Kw = Qw + (size_t)BSROWS * D_MODEL;
    ushort* Vw = Kw + (size_t)BSROWS * D_MODEL;
    float*  Aw = (float*)(Vw + (size_t)BSROWS * D_MODEL);
    // needs 3*8MiB + 16MiB = 40 MiB of ws

    const dim3 gg(BSROWS / 64, D_MODEL / 64);
    gemm_nt<1><<<gg, 256, 0, stream>>>(x, Wq, bq, Qw, 0.125f);   // Q pre-scaled
    gemm_nt<1><<<gg, 256, 0, stream>>>(x, Wk, bk, Kw, 1.0f);
    gemm_nt<2><<<gg, 256, 0, stream>>>(x, Wv, bv, Vw, 1.0f);     // V transposed

    attn_mfma<<<dim3(SEQ / 64, NH, NB), 256, 0, stream>>>(Qw, Kw, Vw, Aw);

    gemm_nt<0><<<gg, 256, 0, stream>>>(Aw, Wo, bo, out, 1.0f);
}

// Round 4
// 196.940 us; speedup vs baseline: 13.9068x; 4.0053x over previous
//
#include <hip/hip_runtime.h>
#include <math.h>

#define D_MODEL 1024
#define NH 16
#define HD 64
#define SEQ 2048
#define NB 2
#define BSROWS (NB * SEQ)   // 4096

typedef __attribute__((ext_vector_type(8))) short short8;
typedef __attribute__((ext_vector_type(4))) float f32x4;

__device__ __forceinline__ ushort bf16rne(float f) {
    union { float f; uint32_t u; } v; v.f = f;
    return (ushort)((v.u + 0x7FFFu + ((v.u >> 16) & 1u)) >> 16);
}

// async global->LDS, 16B per lane. LDS dest = wave-uniform base + lane*16.
__device__ __forceinline__ void gl_lds16(const void* g, void* l) {
    __builtin_amdgcn_global_load_lds(
        reinterpret_cast<const uint32_t __attribute__((address_space(1)))*>(
            reinterpret_cast<uintptr_t>(g)),
        reinterpret_cast<uint32_t __attribute__((address_space(3)))*>(
            reinterpret_cast<uintptr_t>(l)),
        16, 0, 0);
}

// ---------------------------------------------------------------------------
// fp32 -> bf16 converters (memory-bound, 8 elems/thread)
// ---------------------------------------------------------------------------
__global__ __launch_bounds__(256) void convert_x(const float* __restrict__ in,
                                                 ushort* __restrict__ out) {
    const int i = blockIdx.x * 256 + threadIdx.x;    // n8 = 524288
    const float4 a = ((const float4*)in)[2 * i];
    const float4 b = ((const float4*)in)[2 * i + 1];
    union { ushort u[8]; uint4 v; } r;
    r.u[0] = bf16rne(a.x); r.u[1] = bf16rne(a.y); r.u[2] = bf16rne(a.z); r.u[3] = bf16rne(a.w);
    r.u[4] = bf16rne(b.x); r.u[5] = bf16rne(b.y); r.u[6] = bf16rne(b.z); r.u[7] = bf16rne(b.w);
    ((uint4*)out)[i] = r.v;
}

__global__ __launch_bounds__(256) void convert_w(const float* __restrict__ w0,
                                                 const float* __restrict__ w1,
                                                 const float* __restrict__ w2,
                                                 const float* __restrict__ w3,
                                                 ushort* __restrict__ qkv,
                                                 ushort* __restrict__ wo) {
    const int which = blockIdx.y;
    const float* src = (which == 0) ? w0 : (which == 1) ? w1 : (which == 2) ? w2 : w3;
    ushort* dst = (which < 3) ? (qkv + (size_t)which * D_MODEL * D_MODEL) : wo;
    const int i = blockIdx.x * 256 + threadIdx.x;    // n8 = 131072 -> grid.x 512
    const float4 a = ((const float4*)src)[2 * i];
    const float4 b = ((const float4*)src)[2 * i + 1];
    union { ushort u[8]; uint4 v; } r;
    r.u[0] = bf16rne(a.x); r.u[1] = bf16rne(a.y); r.u[2] = bf16rne(a.z); r.u[3] = bf16rne(a.w);
    r.u[4] = bf16rne(b.x); r.u[5] = bf16rne(b.y); r.u[6] = bf16rne(b.z); r.u[7] = bf16rne(b.w);
    ((uint4*)dst)[i] = r.v;
}

// ---------------------------------------------------------------------------
// bf16 MFMA NT-GEMM (m97 structure): C[i,j] = sum_k A[i,k]*B[j,k]
//   BM=128, BK=32, 256 threads (4 waves, 2x2 wave grid), global_load_lds w=16.
// MODE 0 (BN=128): QKV router epilogue. blockIdx.y selects proj p = n0>>10
//   (block-uniform): p=0 -> Q bf16 split-head, *0.125; p=1 -> K bf16
//   split-head; p=2 -> V bf16 transposed [B,H,hd,S].
// MODE 1 (BN=64): fp32 flat out [M][1024] + bias (final O projection).
// ---------------------------------------------------------------------------
template <int BN, int MODE>
__global__ __launch_bounds__(256) void gemm_mfma(const ushort* __restrict__ A,
                                                 const ushort* __restrict__ B,
                                                 const float* __restrict__ b0,
                                                 const float* __restrict__ b1,
                                                 const float* __restrict__ b2,
                                                 void* __restrict__ o0v,
                                                 void* __restrict__ o1v,
                                                 void* __restrict__ o2v) {
    constexpr int BM = 128, BK = 32;
    constexpr int WN = (BN == 128) ? 64 : 32;   // wave tile N
    constexpr int NM = 4;                        // 64/16
    constexpr int NN = WN / 16;                  // 4 or 2

    __shared__ ushort As[BM * BK];
    __shared__ ushort Bs[BN * BK];

    const int tid = threadIdx.x;
    const int w   = tid >> 6;
    const int l   = tid & 63;
    const int i0  = blockIdx.x * BM;
    const int n0  = blockIdx.y * BN;

    const int wr = (w >> 1) * 64;
    const int wc = (w & 1) * WN;

    // staging coords: lane covers 16B; 4 lanes/row; 16 rows per issue
    const int srow = l >> 2;
    const int scol = (l & 3) * 8;   // elems
    const ushort* ga = A + (size_t)(i0 + w * 32 + srow) * D_MODEL + scol;
    const ushort* gb = B + (size_t)(n0 + w * (BN / 4) + srow) * D_MODEL + scol;
    ushort* lA = &As[(w * 32) * BK];
    ushort* lB = &Bs[(w * (BN / 4)) * BK];

    f32x4 acc[NM][NN];
#pragma unroll
    for (int m = 0; m < NM; ++m)
#pragma unroll
        for (int n = 0; n < NN; ++n) acc[m][n] = (f32x4){0.f, 0.f, 0.f, 0.f};

    const int fr = l & 15;
    const int kc = (l >> 4) * 8;

    for (int k0 = 0; k0 < D_MODEL; k0 += BK) {
        __syncthreads();                         // prev tile consumed
        gl_lds16(ga, lA);
        gl_lds16(ga + 16 * D_MODEL, lA + 16 * BK);
        gl_lds16(gb, lB);
        if (BN == 128) gl_lds16(gb + 16 * D_MODEL, lB + 16 * BK);
        ga += BK; gb += BK;
        __syncthreads();                         // staging landed (vmcnt drained)

        short8 af[NM], bfr[NN];
#pragma unroll
        for (int m = 0; m < NM; ++m)
            af[m] = *(const short8*)&As[(wr + m * 16 + fr) * BK + kc];
#pragma unroll
        for (int n = 0; n < NN; ++n)
            bfr[n] = *(const short8*)&Bs[(wc + n * 16 + fr) * BK + kc];
#pragma unroll
        for (int m = 0; m < NM; ++m)
#pragma unroll
            for (int n = 0; n < NN; ++n)
                acc[m][n] = __builtin_amdgcn_mfma_f32_16x16x32_bf16(af[m], bfr[n], acc[m][n], 0, 0, 0);
    }

    // ---- epilogue: C row = i0+wr+m*16+(l>>4)*4+r, col = n0+wc+n*16+(l&15) ----
    const int rr = (l >> 4) * 4;

    if (MODE == 1) {
        float* out = (float*)o0v;
#pragma unroll
        for (int n = 0; n < NN; ++n) {
            const int j = n0 + wc + n * 16 + fr;
            const float bj = b0[j];
#pragma unroll
            for (int m = 0; m < NM; ++m) {
                const int row = i0 + wr + m * 16 + rr;
#pragma unroll
                for (int r = 0; r < 4; ++r)
                    out[(size_t)(row + r) * D_MODEL + j] = acc[m][n][r] + bj;
            }
        }
    } else {
        const int p = n0 >> 10;                  // block-uniform: 0=Q 1=K 2=V
        const float* bias = (p == 0) ? b0 : (p == 1) ? b1 : b2;
        const float scl = (p == 0) ? 0.125f : 1.0f;
#pragma unroll
        for (int n = 0; n < NN; ++n) {
            const int j = n0 + wc + n * 16 + fr;
            const int f = j & 1023;
            const float bj = bias[f];
            const int h = f >> 6, d = f & 63;
#pragma unroll
            for (int m = 0; m < NM; ++m) {
                const int row = i0 + wr + m * 16 + rr;
                const int bb = row >> 11;
                const int s0 = row & (SEQ - 1);
                if (p < 2) {
                    ushort* dst = (ushort*)(p == 0 ? o0v : o1v);
#pragma unroll
                    for (int r = 0; r < 4; ++r)
                        dst[(((size_t)bb * NH + h) * SEQ + (s0 + r)) * HD + d] =
                            bf16rne((acc[m][n][r] + bj) * scl);
                } else {
                    ushort4 pk;
                    pk.x = bf16rne(acc[m][n][0] + bj);
                    pk.y = bf16rne(acc[m][n][1] + bj);
                    pk.z = bf16rne(acc[m][n][2] + bj);
                    pk.w = bf16rne(acc[m][n][3] + bj);
                    *(ushort4*)&((ushort*)o2v)[(((size_t)bb * NH + h) * HD + d) * SEQ + s0] = pk;
                }
            }
        }
    }
}

// ---------------------------------------------------------------------------
// MFMA flash attention (unchanged structure from round 3; output now bf16).
// 4 waves/block, 64 q-rows/block, KV tiles of 64. Q pre-scaled by 1/8.
// Q/K: bf16 [B,H,S,hd]; V: bf16 [B,H,hd,S]. Out: bf16 merged [B*S, D_MODEL].
// LDS tiles XOR-swizzled: elem col ^= (row&7)<<3.
// ---------------------------------------------------------------------------
__global__ __launch_bounds__(256) void attn_mfma(const ushort* __restrict__ Q,
                                                 const ushort* __restrict__ K,
                                                 const ushort* __restrict__ Vt,
                                                 ushort* __restrict__ Aout) {
    __shared__ ushort Qs[64 * 64];
    __shared__ ushort Ks[64 * 64];
    __shared__ ushort Vts[64 * 64];
    __shared__ ushort Ps[4 * 16 * 64];

    const int tid = threadIdx.x;
    const int w   = tid >> 6;
    const int l   = tid & 63;
    const int qt  = blockIdx.x;
    const int h   = blockIdx.y;
    const int b   = blockIdx.z;
    const size_t bh = (size_t)b * NH + h;

    const ushort* Qg = Q  + (bh * SEQ + (size_t)qt * 64) * HD;
    const ushort* Kg = K  + bh * SEQ * HD;
    const ushort* Vg = Vt + bh * HD * SEQ;

    for (int g = tid; g < 512; g += 256) {
        const int row = g >> 3, c = g & 7;
        uint4 v = *(const uint4*)&Qg[row * HD + c * 8];
        *(uint4*)&Qs[row * 64 + ((c * 8) ^ ((row & 7) << 3))] = v;
    }

    const int g16  = l >> 4;
    const int c16  = l & 15;
    const int kcol = g16 * 8;

    f32x4 o_acc[4];
#pragma unroll
    for (int dd = 0; dd < 4; ++dd) o_acc[dd] = (f32x4){0.f, 0.f, 0.f, 0.f};
    float m[4], lsum[4];
#pragma unroll
    for (int r = 0; r < 4; ++r) { m[r] = -INFINITY; lsum[r] = 0.f; }

    for (int kt = 0; kt < SEQ / 64; ++kt) {
        __syncthreads();
        const ushort* Kt = Kg + (size_t)kt * 64 * HD;
        for (int g = tid; g < 512; g += 256) {
            const int row = g >> 3, c = g & 7;
            uint4 v = *(const uint4*)&Kt[row * HD + c * 8];
            *(uint4*)&Ks[row * 64 + ((c * 8) ^ ((row & 7) << 3))] = v;
        }
        for (int g = tid; g < 512; g += 256) {
            const int row = g >> 3, c = g & 7;   // row = d
            uint4 v = *(const uint4*)&Vg[(size_t)row * SEQ + kt * 64 + c * 8];
            *(uint4*)&Vts[row * 64 + ((c * 8) ^ ((row & 7) << 3))] = v;
        }
        __syncthreads();

        f32x4 s[4];
#pragma unroll
        for (int tt = 0; tt < 4; ++tt) s[tt] = (f32x4){0.f, 0.f, 0.f, 0.f};
#pragma unroll
        for (int kcx = 0; kcx < 2; ++kcx) {
            const int qrow = w * 16 + c16;
            const short8 aq = *(const short8*)&Qs[qrow * 64 + ((kcx * 32 + kcol) ^ ((qrow & 7) << 3))];
#pragma unroll
            for (int tt = 0; tt < 4; ++tt) {
                const int krow = tt * 16 + c16;
                const short8 bk = *(const short8*)&Ks[krow * 64 + ((kcx * 32 + kcol) ^ ((krow & 7) << 3))];
                s[tt] = __builtin_amdgcn_mfma_f32_16x16x32_bf16(aq, bk, s[tt], 0, 0, 0);
            }
        }

        float cm[4];
#pragma unroll
        for (int r = 0; r < 4; ++r)
            cm[r] = fmaxf(fmaxf(s[0][r], s[1][r]), fmaxf(s[2][r], s[3][r]));
#pragma unroll
        for (int off = 8; off >= 1; off >>= 1)
#pragma unroll
            for (int r = 0; r < 4; ++r) cm[r] = fmaxf(cm[r], __shfl_xor(cm[r], off));

        float corr[4];
#pragma unroll
        for (int r = 0; r < 4; ++r) {
            const float mn = fmaxf(m[r], cm[r]);
            corr[r] = __expf(m[r] - mn);
            m[r] = mn;
        }
        float ps[4] = {0.f, 0.f, 0.f, 0.f};
#pragma unroll
        for (int tt = 0; tt < 4; ++tt)
#pragma unroll
            for (int r = 0; r < 4; ++r) {
                const float p = __expf(s[tt][r] - m[r]);
                s[tt][r] = p;
                ps[r] += p;
            }
#pragma unroll
        for (int off = 8; off >= 1; off >>= 1)
#pragma unroll
            for (int r = 0; r < 4; ++r) ps[r] += __shfl_xor(ps[r], off);
#pragma unroll
        for (int r = 0; r < 4; ++r) lsum[r] = lsum[r] * corr[r] + ps[r];
#pragma unroll
        for (int dd = 0; dd < 4; ++dd)
#pragma unroll
            for (int r = 0; r < 4; ++r) o_acc[dd][r] *= corr[r];

#pragma unroll
        for (int tt = 0; tt < 4; ++tt)
#pragma unroll
            for (int r = 0; r < 4; ++r) {
                const int q = g16 * 4 + r;
                const int t = c16 + tt * 16;
                Ps[w * 1024 + q * 64 + (t ^ ((q & 7) << 3))] = bf16rne(s[tt][r]);
            }

#pragma unroll
        for (int kcx = 0; kcx < 2; ++kcx) {
            const int prow = c16;
            const short8 ap = *(const short8*)&Ps[w * 1024 + prow * 64 + ((kcx * 32 + kcol) ^ ((prow & 7) << 3))];
#pragma unroll
            for (int dd = 0; dd < 4; ++dd) {
                const int vrow = dd * 16 + c16;
                const short8 bv = *(const short8*)&Vts[vrow * 64 + ((kcx * 32 + kcol) ^ ((vrow & 7) << 3))];
                o_acc[dd] = __builtin_amdgcn_mfma_f32_16x16x32_bf16(ap, bv, o_acc[dd], 0, 0, 0);
            }
        }
    }

#pragma unroll
    for (int r = 0; r < 4; ++r) {
        const float inv = 1.f / lsum[r];
        const size_t row = (size_t)b * SEQ + qt * 64 + w * 16 + g16 * 4 + r;
#pragma unroll
        for (int dd = 0; dd < 4; ++dd)
            Aout[row * D_MODEL + h * HD + c16 + dd * 16] = bf16rne(o_acc[dd][r] * inv);
    }
}

// ---------------------------------------------------------------------------
extern "C" void kernel_launch(void* const* d_in, const int* in_sizes, int n_in,
                              void* d_out, int out_size, void* d_ws, size_t ws_size,
                              hipStream_t stream) {
    const float* x  = (const float*)d_in[0];
    const float* Wq = (const float*)d_in[1];
    const float* bq = (const float*)d_in[2];
    const float* Wk = (const float*)d_in[3];
    const float* bk = (const float*)d_in[4];
    const float* Wv = (const float*)d_in[5];
    const float* bv = (const float*)d_in[6];
    const float* Wo = (const float*)d_in[7];
    const float* bo = (const float*)d_in[8];
    float* out = (float*)d_out;

    // ws layout (bf16 ushorts): xb 8M | Wqkv 6M | Wob 2M | Qw 8M | Kw 8M | Vw 8M | Ab 8M = 48 MiB
    ushort* xb   = (ushort*)d_ws;
    ushort* Wqkv = xb   + (size_t)BSROWS * D_MODEL;
    ushort* Wob  = Wqkv + (size_t)3 * D_MODEL * D_MODEL;
    ushort* Qw   = Wob  + (size_t)D_MODEL * D_MODEL;
    ushort* Kw   = Qw   + (size_t)BSROWS * D_MODEL;
    ushort* Vw   = Kw   + (size_t)BSROWS * D_MODEL;
    ushort* Ab   = Vw   + (size_t)BSROWS * D_MODEL;

    convert_w<<<dim3(512, 4), 256, 0, stream>>>(Wq, Wk, Wv, Wo, Wqkv, Wob);
    convert_x<<<dim3(2048), 256, 0, stream>>>(x, xb);

    // fused QKV projection: N = 3072, grid (32,24) = 768 blocks
    gemm_mfma<128, 0><<<dim3(32, 24), 256, 0, stream>>>(
        xb, Wqkv, bq, bk, bv, Qw, Kw, Vw);

    attn_mfma<<<dim3(SEQ / 64, NH, NB), 256, 0, stream>>>(Qw, Kw, Vw, Ab);

    // O projection: N = 1024, BN=64 -> grid (32,16) = 512 blocks
    gemm_mfma<64, 1><<<dim3(32, 16), 256, 0, stream>>>(
        Ab, Wob, bo, nullptr, nullptr, out, nullptr, nullptr);
}

// Round 5
// 169.029 us; speedup vs baseline: 16.2032x; 1.1651x over previous
//
#include <hip/hip_runtime.h>
#include <math.h>

#define D_MODEL 1024
#define NH 16
#define HD 64
#define SEQ 2048
#define NB 2
#define BSROWS (NB * SEQ)   // 4096
#define NT (SEQ / 64)       // 32 KV tiles

typedef __attribute__((ext_vector_type(8)))  short short8;
typedef __attribute__((ext_vector_type(4)))  float f32x4;
typedef __attribute__((ext_vector_type(16))) float f32x16;

__device__ __forceinline__ ushort bf16rne(float f) {
    union { float f; uint32_t u; } v; v.f = f;
    return (ushort)((v.u + 0x7FFFu + ((v.u >> 16) & 1u)) >> 16);
}

// async global->LDS, 16B per lane. LDS dest = wave-uniform base + lane*16.
__device__ __forceinline__ void gl_lds16(const void* g, void* l) {
    __builtin_amdgcn_global_load_lds(
        reinterpret_cast<const uint32_t __attribute__((address_space(1)))*>(
            reinterpret_cast<uintptr_t>(g)),
        reinterpret_cast<uint32_t __attribute__((address_space(3)))*>(
            reinterpret_cast<uintptr_t>(l)),
        16, 0, 0);
}

// ---------------------------------------------------------------------------
// fp32 -> bf16 converters
// ---------------------------------------------------------------------------
__global__ __launch_bounds__(256) void convert_x(const float* __restrict__ in,
                                                 ushort* __restrict__ out) {
    const int i = blockIdx.x * 256 + threadIdx.x;
    const float4 a = ((const float4*)in)[2 * i];
    const float4 b = ((const float4*)in)[2 * i + 1];
    union { ushort u[8]; uint4 v; } r;
    r.u[0] = bf16rne(a.x); r.u[1] = bf16rne(a.y); r.u[2] = bf16rne(a.z); r.u[3] = bf16rne(a.w);
    r.u[4] = bf16rne(b.x); r.u[5] = bf16rne(b.y); r.u[6] = bf16rne(b.z); r.u[7] = bf16rne(b.w);
    ((uint4*)out)[i] = r.v;
}

__global__ __launch_bounds__(256) void convert_w(const float* __restrict__ w0,
                                                 const float* __restrict__ w1,
                                                 const float* __restrict__ w2,
                                                 const float* __restrict__ w3,
                                                 ushort* __restrict__ qkv,
                                                 ushort* __restrict__ wo) {
    const int which = blockIdx.y;
    const float* src = (which == 0) ? w0 : (which == 1) ? w1 : (which == 2) ? w2 : w3;
    ushort* dst = (which < 3) ? (qkv + (size_t)which * D_MODEL * D_MODEL) : wo;
    const int i = blockIdx.x * 256 + threadIdx.x;
    const float4 a = ((const float4*)src)[2 * i];
    const float4 b = ((const float4*)src)[2 * i + 1];
    union { ushort u[8]; uint4 v; } r;
    r.u[0] = bf16rne(a.x); r.u[1] = bf16rne(a.y); r.u[2] = bf16rne(a.z); r.u[3] = bf16rne(a.w);
    r.u[4] = bf16rne(b.x); r.u[5] = bf16rne(b.y); r.u[6] = bf16rne(b.z); r.u[7] = bf16rne(b.w);
    ((uint4*)dst)[i] = r.v;
}

// ---------------------------------------------------------------------------
// bf16 MFMA NT-GEMM (m97 structure) — unchanged from round 4 (verified).
// ---------------------------------------------------------------------------
template <int BN, int MODE>
__global__ __launch_bounds__(256) void gemm_mfma(const ushort* __restrict__ A,
                                                 const ushort* __restrict__ B,
                                                 const float* __restrict__ b0,
                                                 const float* __restrict__ b1,
                                                 const float* __restrict__ b2,
                                                 void* __restrict__ o0v,
                                                 void* __restrict__ o1v,
                                                 void* __restrict__ o2v) {
    constexpr int BM = 128, BK = 32;
    constexpr int WN = (BN == 128) ? 64 : 32;
    constexpr int NM = 4;
    constexpr int NN = WN / 16;

    __shared__ ushort As[BM * BK];
    __shared__ ushort Bs[BN * BK];

    const int tid = threadIdx.x;
    const int w   = tid >> 6;
    const int l   = tid & 63;
    const int i0  = blockIdx.x * BM;
    const int n0  = blockIdx.y * BN;

    const int wr = (w >> 1) * 64;
    const int wc = (w & 1) * WN;

    const int srow = l >> 2;
    const int scol = (l & 3) * 8;
    const ushort* ga = A + (size_t)(i0 + w * 32 + srow) * D_MODEL + scol;
    const ushort* gb = B + (size_t)(n0 + w * (BN / 4) + srow) * D_MODEL + scol;
    ushort* lA = &As[(w * 32) * BK];
    ushort* lB = &Bs[(w * (BN / 4)) * BK];

    f32x4 acc[NM][NN];
#pragma unroll
    for (int m = 0; m < NM; ++m)
#pragma unroll
        for (int n = 0; n < NN; ++n) acc[m][n] = (f32x4){0.f, 0.f, 0.f, 0.f};

    const int fr = l & 15;
    const int kc = (l >> 4) * 8;

    for (int k0 = 0; k0 < D_MODEL; k0 += BK) {
        __syncthreads();
        gl_lds16(ga, lA);
        gl_lds16(ga + 16 * D_MODEL, lA + 16 * BK);
        gl_lds16(gb, lB);
        if (BN == 128) gl_lds16(gb + 16 * D_MODEL, lB + 16 * BK);
        ga += BK; gb += BK;
        __syncthreads();

        short8 af[NM], bfr[NN];
#pragma unroll
        for (int m = 0; m < NM; ++m)
            af[m] = *(const short8*)&As[(wr + m * 16 + fr) * BK + kc];
#pragma unroll
        for (int n = 0; n < NN; ++n)
            bfr[n] = *(const short8*)&Bs[(wc + n * 16 + fr) * BK + kc];
#pragma unroll
        for (int m = 0; m < NM; ++m)
#pragma unroll
            for (int n = 0; n < NN; ++n)
                acc[m][n] = __builtin_amdgcn_mfma_f32_16x16x32_bf16(af[m], bfr[n], acc[m][n], 0, 0, 0);
    }

    const int rr = (l >> 4) * 4;

    if (MODE == 1) {
        float* out = (float*)o0v;
#pragma unroll
        for (int n = 0; n < NN; ++n) {
            const int j = n0 + wc + n * 16 + fr;
            const float bj = b0[j];
#pragma unroll
            for (int m = 0; m < NM; ++m) {
                const int row = i0 + wr + m * 16 + rr;
#pragma unroll
                for (int r = 0; r < 4; ++r)
                    out[(size_t)(row + r) * D_MODEL + j] = acc[m][n][r] + bj;
            }
        }
    } else {
        const int p = n0 >> 10;
        const float* bias = (p == 0) ? b0 : (p == 1) ? b1 : b2;
        const float scl = (p == 0) ? 0.125f : 1.0f;
#pragma unroll
        for (int n = 0; n < NN; ++n) {
            const int j = n0 + wc + n * 16 + fr;
            const int f = j & 1023;
            const float bj = bias[f];
            const int h = f >> 6, d = f & 63;
#pragma unroll
            for (int m = 0; m < NM; ++m) {
                const int row = i0 + wr + m * 16 + rr;
                const int bb = row >> 11;
                const int s0 = row & (SEQ - 1);
                if (p < 2) {
                    ushort* dst = (ushort*)(p == 0 ? o0v : o1v);
#pragma unroll
                    for (int r = 0; r < 4; ++r)
                        dst[(((size_t)bb * NH + h) * SEQ + (s0 + r)) * HD + d] =
                            bf16rne((acc[m][n][r] + bj) * scl);
                } else {
                    ushort4 pk;
                    pk.x = bf16rne(acc[m][n][0] + bj);
                    pk.y = bf16rne(acc[m][n][1] + bj);
                    pk.z = bf16rne(acc[m][n][2] + bj);
                    pk.w = bf16rne(acc[m][n][3] + bj);
                    *(ushort4*)&((ushort*)o2v)[(((size_t)bb * NH + h) * HD + d) * SEQ + s0] = pk;
                }
            }
        }
    }
}

// ---------------------------------------------------------------------------
// Swapped-QK^T 32x32 MFMA flash attention, in-register softmax (T12/T13/T14).
// 4 waves/block, 32 q-rows/wave (128/block). KV tile 64, sub-tiles of 32.
// Q/K bf16 [B,H,S,hd] (Q pre-scaled); V bf16 [B,H,hd,S]. Out bf16 [B*S, D].
//   S^T = mfma_32x32x16(K_frag_A, Q_frag_B): lane owns col q = l&31.
//   P kept in regs; PV B-operand built via cvt_pk + shfl_xor(32) exchange.
//   O^T = mfma(Vt_frag_A, P_frag_B), col q = l&31; transposed out via LDS.
// ---------------------------------------------------------------------------
__global__ __launch_bounds__(256) void attn_mfma2(const ushort* __restrict__ Q,
                                                  const ushort* __restrict__ K,
                                                  const ushort* __restrict__ Vt,
                                                  ushort* __restrict__ Aout) {
    __shared__ ushort smem[8192];          // Ks [64][64] | Vts [64][64]
    ushort* Ks  = smem;
    ushort* Vts = smem + 4096;

    const int tid = threadIdx.x;
    const int w   = tid >> 6;
    const int l   = tid & 63;
    const int lq  = l & 31;                // lane's q column / frag row
    const int hi  = l >> 5;
    const int qt  = blockIdx.x;
    const int h   = blockIdx.y;
    const int b   = blockIdx.z;
    const size_t bh = (size_t)b * NH + h;

    const ushort* Qg = Q  + (bh * SEQ + (size_t)qt * 128 + w * 32 + lq) * HD;
    const ushort* Kg = K  + bh * SEQ * HD;
    const ushort* Vg = Vt + bh * HD * SEQ;

    // Q B-fragments (loop-invariant): lane holds Q[q=lq][d = dk*16 + hi*8 + j]
    short8 qf[4];
#pragma unroll
    for (int dk = 0; dk < 4; ++dk)
        qf[dk] = *(const short8*)&Qg[dk * 16 + hi * 8];

    // staging assignment: 2 chunks (16B) each of K and V per thread
    int srow[2], scol[2];
#pragma unroll
    for (int j = 0; j < 2; ++j) {
        const int idx = tid + j * 256;
        srow[j] = idx >> 3;
        scol[j] = (idx & 7) * 8;
    }
    uint4 kreg[2], vreg[2];
#pragma unroll
    for (int j = 0; j < 2; ++j) {          // prologue: tile 0
        kreg[j] = *(const uint4*)&Kg[(size_t)srow[j] * HD + scol[j]];
        vreg[j] = *(const uint4*)&Vg[(size_t)srow[j] * SEQ + scol[j]];
    }

    f32x16 oa0, oa1;
#pragma unroll
    for (int r = 0; r < 16; ++r) { oa0[r] = 0.f; oa1[r] = 0.f; }
    float m = -3.0e38f, lsum = 0.f;

    for (int kt = 0; kt < NT; ++kt) {
        __syncthreads();                   // prev tile's compute done
#pragma unroll
        for (int j = 0; j < 2; ++j) {      // write staged regs -> LDS (swizzled)
            const int sw = (srow[j] & 7) << 3;
            *(uint4*)&Ks [srow[j] * 64 + (scol[j] ^ sw)] = kreg[j];
            *(uint4*)&Vts[srow[j] * 64 + (scol[j] ^ sw)] = vreg[j];
        }
        __syncthreads();                   // staging visible
        if (kt + 1 < NT) {                 // T14: issue next-tile loads early
#pragma unroll
            for (int j = 0; j < 2; ++j) {
                kreg[j] = *(const uint4*)&Kg[((size_t)(kt + 1) * 64 + srow[j]) * HD + scol[j]];
                vreg[j] = *(const uint4*)&Vg[(size_t)srow[j] * SEQ + (kt + 1) * 64 + scol[j]];
            }
        }

#pragma unroll
        for (int sub = 0; sub < 2; ++sub) {
            // ---- QK^T: S^T[t][q], 32x32 ----
            f32x16 sc;
#pragma unroll
            for (int r = 0; r < 16; ++r) sc[r] = 0.f;
            const int trow = sub * 32 + lq;
            const int ksw  = (trow & 7) << 3;
#pragma unroll
            for (int dk = 0; dk < 4; ++dk) {
                const short8 kf = *(const short8*)&Ks[trow * 64 + ((dk * 16 + hi * 8) ^ ksw)];
                sc = __builtin_amdgcn_mfma_f32_32x32x16_bf16(kf, qf[dk], sc, 0, 0, 0);
            }

            // ---- row max: 15 local + 1 partner exchange ----
            float t0 = fmaxf(fmaxf(sc[0], sc[1]), fmaxf(sc[2], sc[3]));
            float t1 = fmaxf(fmaxf(sc[4], sc[5]), fmaxf(sc[6], sc[7]));
            float t2 = fmaxf(fmaxf(sc[8], sc[9]), fmaxf(sc[10], sc[11]));
            float t3 = fmaxf(fmaxf(sc[12], sc[13]), fmaxf(sc[14], sc[15]));
            float pm = fmaxf(fmaxf(t0, t1), fmaxf(t2, t3));
            pm = fmaxf(pm, __shfl_xor(pm, 32));

            // ---- T13 defer-max: rescale only when max grows > 8 ----
            if (!__all(pm - m <= 8.0f)) {
                const float mn = fmaxf(m, pm);
                const float corr = __expf(m - mn);
                m = mn; lsum *= corr;
#pragma unroll
                for (int r = 0; r < 16; ++r) { oa0[r] *= corr; oa1[r] *= corr; }
            }

            // ---- exp + per-lane partial sum ----
            float p[16];
#pragma unroll
            for (int r = 0; r < 16; ++r) p[r] = __expf(sc[r] - m);
            lsum += (((p[0] + p[1]) + (p[2] + p[3])) + ((p[4] + p[5]) + (p[6] + p[7])))
                  + (((p[8] + p[9]) + (p[10] + p[11])) + ((p[12] + p[13]) + (p[14] + p[15])));

            // ---- pack P -> bf16 pairs, exchange halves across lane^32 ----
            uint32_t pk[8];
#pragma unroll
            for (int i = 0; i < 8; ++i)
                asm("v_cvt_pk_bf16_f32 %0, %1, %2" : "=v"(pk[i]) : "v"(p[2 * i]), "v"(p[2 * i + 1]));
            uint32_t x[8];
#pragma unroll
            for (int i = 0; i < 8; ++i) x[i] = __shfl_xor(pk[i], 32);

            union U8 { uint32_t u[4]; short8 s; };
            U8 f0, f1;
            f0.u[0] = hi ? x[2]  : pk[0];  f0.u[1] = hi ? x[3]  : pk[1];
            f0.u[2] = hi ? pk[2] : x[0];   f0.u[3] = hi ? pk[3] : x[1];
            f1.u[0] = hi ? x[6]  : pk[4];  f1.u[1] = hi ? x[7]  : pk[5];
            f1.u[2] = hi ? pk[6] : x[4];   f1.u[3] = hi ? pk[7] : x[5];
            const short8 pf0 = f0.s, pf1 = f1.s;

            // ---- PV: O^T[d][q] += Vt[d][t] * P[q][t] ----
            const int d0 = lq,        vsw0 = (d0 & 7) << 3;
            const int d1 = 32 + lq,   vsw1 = (d1 & 7) << 3;
            {
                const int tb = sub * 32 + hi * 8;
                const short8 vA0 = *(const short8*)&Vts[d0 * 64 + ((tb)      ^ vsw0)];
                const short8 vA1 = *(const short8*)&Vts[d1 * 64 + ((tb)      ^ vsw1)];
                const short8 vB0 = *(const short8*)&Vts[d0 * 64 + ((tb + 16) ^ vsw0)];
                const short8 vB1 = *(const short8*)&Vts[d1 * 64 + ((tb + 16) ^ vsw1)];
                oa0 = __builtin_amdgcn_mfma_f32_32x32x16_bf16(vA0, pf0, oa0, 0, 0, 0);
                oa1 = __builtin_amdgcn_mfma_f32_32x32x16_bf16(vA1, pf0, oa1, 0, 0, 0);
                oa0 = __builtin_amdgcn_mfma_f32_32x32x16_bf16(vB0, pf1, oa0, 0, 0, 0);
                oa1 = __builtin_amdgcn_mfma_f32_32x32x16_bf16(vB1, pf1, oa1, 0, 0, 0);
            }
        }
    }

    // ---- epilogue: final sum exchange, normalize, LDS transpose, store ----
    lsum += __shfl_xor(lsum, 32);
    const float inv = 1.f / lsum;

    __syncthreads();                       // all waves done with Ks/Vts
    ushort* Ow = smem + w * 2048;          // per-wave 32x64 region
#pragma unroll
    for (int r = 0; r < 16; ++r) {
        const int dd = (r & 3) + 8 * (r >> 2) + 4 * hi;
        const int swq = (lq & 7) << 3;
        Ow[lq * 64 + ((dd)      ^ swq)] = bf16rne(oa0[r] * inv);
        Ow[lq * 64 + ((dd + 32) ^ swq)] = bf16rne(oa1[r] * inv);
    }
    const size_t orow0 = (size_t)b * SEQ + (size_t)qt * 128 + w * 32;
#pragma unroll
    for (int i = 0; i < 4; ++i) {
        const int row = (l >> 3) + 8 * i;
        const int d0 = (l & 7) * 8;
        const uint4 v = *(const uint4*)&Ow[row * 64 + (d0 ^ ((row & 7) << 3))];
        *(uint4*)&Aout[(orow0 + row) * D_MODEL + h * HD + d0] = v;
    }
}

// ---------------------------------------------------------------------------
extern "C" void kernel_launch(void* const* d_in, const int* in_sizes, int n_in,
                              void* d_out, int out_size, void* d_ws, size_t ws_size,
                              hipStream_t stream) {
    const float* x  = (const float*)d_in[0];
    const float* Wq = (const float*)d_in[1];
    const float* bq = (const float*)d_in[2];
    const float* Wk = (const float*)d_in[3];
    const float* bk = (const float*)d_in[4];
    const float* Wv = (const float*)d_in[5];
    const float* bv = (const float*)d_in[6];
    const float* Wo = (const float*)d_in[7];
    const float* bo = (const float*)d_in[8];
    float* out = (float*)d_out;

    ushort* xb   = (ushort*)d_ws;
    ushort* Wqkv = xb   + (size_t)BSROWS * D_MODEL;
    ushort* Wob  = Wqkv + (size_t)3 * D_MODEL * D_MODEL;
    ushort* Qw   = Wob  + (size_t)D_MODEL * D_MODEL;
    ushort* Kw   = Qw   + (size_t)BSROWS * D_MODEL;
    ushort* Vw   = Kw   + (size_t)BSROWS * D_MODEL;
    ushort* Ab   = Vw   + (size_t)BSROWS * D_MODEL;

    convert_w<<<dim3(512, 4), 256, 0, stream>>>(Wq, Wk, Wv, Wo, Wqkv, Wob);
    convert_x<<<dim3(2048), 256, 0, stream>>>(x, xb);

    gemm_mfma<128, 0><<<dim3(32, 24), 256, 0, stream>>>(
        xb, Wqkv, bq, bk, bv, Qw, Kw, Vw);

    attn_mfma2<<<dim3(SEQ / 128, NH, NB), 256, 0, stream>>>(Qw, Kw, Vw, Ab);

    gemm_mfma<64, 1><<<dim3(32, 16), 256, 0, stream>>>(
        Ab, Wob, bo, nullptr, nullptr, out, nullptr, nullptr);
}

// Round 6
// 144.278 us; speedup vs baseline: 18.9829x; 1.1715x over previous
//
#include <hip/hip_runtime.h>
#include <math.h>

#define D_MODEL 1024
#define NH 16
#define HD 64
#define SEQ 2048
#define NB 2
#define BSROWS (NB * SEQ)   // 4096
#define NT (SEQ / 64)       // 32 KV tiles

typedef __attribute__((ext_vector_type(8)))  short short8;
typedef __attribute__((ext_vector_type(4)))  float f32x4;
typedef __attribute__((ext_vector_type(16))) float f32x16;

__device__ __forceinline__ ushort bf16rne(float f) {
    union { float f; uint32_t u; } v; v.f = f;
    return (ushort)((v.u + 0x7FFFu + ((v.u >> 16) & 1u)) >> 16);
}

// async global->LDS, 16B per lane. LDS dest = wave-uniform base + lane*16.
__device__ __forceinline__ void gl_lds16(const void* g, void* l) {
    __builtin_amdgcn_global_load_lds(
        reinterpret_cast<const uint32_t __attribute__((address_space(1)))*>(
            reinterpret_cast<uintptr_t>(g)),
        reinterpret_cast<uint32_t __attribute__((address_space(3)))*>(
            reinterpret_cast<uintptr_t>(l)),
        16, 0, 0);
}

// ---------------------------------------------------------------------------
// fp32 -> bf16 converters
// ---------------------------------------------------------------------------
__global__ __launch_bounds__(256) void convert_x(const float* __restrict__ in,
                                                 ushort* __restrict__ out) {
    const int i = blockIdx.x * 256 + threadIdx.x;
    const float4 a = ((const float4*)in)[2 * i];
    const float4 b = ((const float4*)in)[2 * i + 1];
    union { ushort u[8]; uint4 v; } r;
    r.u[0] = bf16rne(a.x); r.u[1] = bf16rne(a.y); r.u[2] = bf16rne(a.z); r.u[3] = bf16rne(a.w);
    r.u[4] = bf16rne(b.x); r.u[5] = bf16rne(b.y); r.u[6] = bf16rne(b.z); r.u[7] = bf16rne(b.w);
    ((uint4*)out)[i] = r.v;
}

__global__ __launch_bounds__(256) void convert_w(const float* __restrict__ w0,
                                                 const float* __restrict__ w1,
                                                 const float* __restrict__ w2,
                                                 const float* __restrict__ w3,
                                                 ushort* __restrict__ qkv,
                                                 ushort* __restrict__ wo) {
    const int which = blockIdx.y;
    const float* src = (which == 0) ? w0 : (which == 1) ? w1 : (which == 2) ? w2 : w3;
    ushort* dst = (which < 3) ? (qkv + (size_t)which * D_MODEL * D_MODEL) : wo;
    const int i = blockIdx.x * 256 + threadIdx.x;
    const float4 a = ((const float4*)src)[2 * i];
    const float4 b = ((const float4*)src)[2 * i + 1];
    union { ushort u[8]; uint4 v; } r;
    r.u[0] = bf16rne(a.x); r.u[1] = bf16rne(a.y); r.u[2] = bf16rne(a.z); r.u[3] = bf16rne(a.w);
    r.u[4] = bf16rne(b.x); r.u[5] = bf16rne(b.y); r.u[6] = bf16rne(b.z); r.u[7] = bf16rne(b.w);
    ((uint4*)dst)[i] = r.v;
}

// ---------------------------------------------------------------------------
// bf16 MFMA NT-GEMM (m97 structure) — unchanged (validated round 4/5).
// ---------------------------------------------------------------------------
template <int BN, int MODE>
__global__ __launch_bounds__(256) void gemm_mfma(const ushort* __restrict__ A,
                                                 const ushort* __restrict__ B,
                                                 const float* __restrict__ b0,
                                                 const float* __restrict__ b1,
                                                 const float* __restrict__ b2,
                                                 void* __restrict__ o0v,
                                                 void* __restrict__ o1v,
                                                 void* __restrict__ o2v) {
    constexpr int BM = 128, BK = 32;
    constexpr int WN = (BN == 128) ? 64 : 32;
    constexpr int NM = 4;
    constexpr int NN = WN / 16;

    __shared__ ushort As[BM * BK];
    __shared__ ushort Bs[BN * BK];

    const int tid = threadIdx.x;
    const int w   = tid >> 6;
    const int l   = tid & 63;
    const int i0  = blockIdx.x * BM;
    const int n0  = blockIdx.y * BN;

    const int wr = (w >> 1) * 64;
    const int wc = (w & 1) * WN;

    const int srow = l >> 2;
    const int scol = (l & 3) * 8;
    const ushort* ga = A + (size_t)(i0 + w * 32 + srow) * D_MODEL + scol;
    const ushort* gb = B + (size_t)(n0 + w * (BN / 4) + srow) * D_MODEL + scol;
    ushort* lA = &As[(w * 32) * BK];
    ushort* lB = &Bs[(w * (BN / 4)) * BK];

    f32x4 acc[NM][NN];
#pragma unroll
    for (int m = 0; m < NM; ++m)
#pragma unroll
        for (int n = 0; n < NN; ++n) acc[m][n] = (f32x4){0.f, 0.f, 0.f, 0.f};

    const int fr = l & 15;
    const int kc = (l >> 4) * 8;

    for (int k0 = 0; k0 < D_MODEL; k0 += BK) {
        __syncthreads();
        gl_lds16(ga, lA);
        gl_lds16(ga + 16 * D_MODEL, lA + 16 * BK);
        gl_lds16(gb, lB);
        if (BN == 128) gl_lds16(gb + 16 * D_MODEL, lB + 16 * BK);
        ga += BK; gb += BK;
        __syncthreads();

        short8 af[NM], bfr[NN];
#pragma unroll
        for (int m = 0; m < NM; ++m)
            af[m] = *(const short8*)&As[(wr + m * 16 + fr) * BK + kc];
#pragma unroll
        for (int n = 0; n < NN; ++n)
            bfr[n] = *(const short8*)&Bs[(wc + n * 16 + fr) * BK + kc];
#pragma unroll
        for (int m = 0; m < NM; ++m)
#pragma unroll
            for (int n = 0; n < NN; ++n)
                acc[m][n] = __builtin_amdgcn_mfma_f32_16x16x32_bf16(af[m], bfr[n], acc[m][n], 0, 0, 0);
    }

    const int rr = (l >> 4) * 4;

    if (MODE == 1) {
        float* out = (float*)o0v;
#pragma unroll
        for (int n = 0; n < NN; ++n) {
            const int j = n0 + wc + n * 16 + fr;
            const float bj = b0[j];
#pragma unroll
            for (int m = 0; m < NM; ++m) {
                const int row = i0 + wr + m * 16 + rr;
#pragma unroll
                for (int r = 0; r < 4; ++r)
                    out[(size_t)(row + r) * D_MODEL + j] = acc[m][n][r] + bj;
            }
        }
    } else {
        const int p = n0 >> 10;
        const float* bias = (p == 0) ? b0 : (p == 1) ? b1 : b2;
        const float scl = (p == 0) ? 0.125f : 1.0f;
#pragma unroll
        for (int n = 0; n < NN; ++n) {
            const int j = n0 + wc + n * 16 + fr;
            const int f = j & 1023;
            const float bj = bias[f];
            const int h = f >> 6, d = f & 63;
#pragma unroll
            for (int m = 0; m < NM; ++m) {
                const int row = i0 + wr + m * 16 + rr;
                const int bb = row >> 11;
                const int s0 = row & (SEQ - 1);
                if (p < 2) {
                    ushort* dst = (ushort*)(p == 0 ? o0v : o1v);
#pragma unroll
                    for (int r = 0; r < 4; ++r)
                        dst[(((size_t)bb * NH + h) * SEQ + (s0 + r)) * HD + d] =
                            bf16rne((acc[m][n][r] + bj) * scl);
                } else {
                    ushort4 pk;
                    pk.x = bf16rne(acc[m][n][0] + bj);
                    pk.y = bf16rne(acc[m][n][1] + bj);
                    pk.z = bf16rne(acc[m][n][2] + bj);
                    pk.w = bf16rne(acc[m][n][3] + bj);
                    *(ushort4*)&((ushort*)o2v)[(((size_t)bb * NH + h) * HD + d) * SEQ + s0] = pk;
                }
            }
        }
    }
}

// ---------------------------------------------------------------------------
// Swapped-QK^T 32x32 MFMA flash attention — round-6 schedule:
// double-buffered K/V LDS (1 barrier/tile), interleaved sub-tiles (MFMA ILP),
// setprio around MFMA clusters. Math identical to validated round-5 kernel.
// ---------------------------------------------------------------------------
__global__ __launch_bounds__(256) void attn_mfma3(const ushort* __restrict__ Q,
                                                  const ushort* __restrict__ K,
                                                  const ushort* __restrict__ Vt,
                                                  ushort* __restrict__ Aout) {
    __shared__ ushort KsB[2 * 4096];       // [buf][64 rows][64 cols] swizzled
    __shared__ ushort VtsB[2 * 4096];

    const int tid = threadIdx.x;
    const int w   = tid >> 6;
    const int l   = tid & 63;
    const int lq  = l & 31;
    const int hi  = l >> 5;
    const int qt  = blockIdx.x;
    const int h   = blockIdx.y;
    const int b   = blockIdx.z;
    const size_t bh = (size_t)b * NH + h;

    const ushort* Qg = Q  + (bh * SEQ + (size_t)qt * 128 + w * 32 + lq) * HD;
    const ushort* Kg = K  + bh * SEQ * HD;
    const ushort* Vg = Vt + bh * HD * SEQ;

    // Q B-fragments (loop-invariant)
    short8 qf[4];
#pragma unroll
    for (int dk = 0; dk < 4; ++dk)
        qf[dk] = *(const short8*)&Qg[dk * 16 + hi * 8];

    // staging: 2 chunks (16B) each of K and V per thread
    int srow[2], scol[2], ssw[2];
#pragma unroll
    for (int j = 0; j < 2; ++j) {
        const int idx = tid + j * 256;
        srow[j] = idx >> 3;
        scol[j] = (idx & 7) * 8;
        ssw[j]  = scol[j] ^ ((srow[j] & 7) << 3);
    }

    uint4 kreg[2], vreg[2];
#pragma unroll
    for (int j = 0; j < 2; ++j) {          // prologue: tile 0 -> buf 0
        kreg[j] = *(const uint4*)&Kg[(size_t)srow[j] * HD + scol[j]];
        vreg[j] = *(const uint4*)&Vg[(size_t)srow[j] * SEQ + scol[j]];
    }
#pragma unroll
    for (int j = 0; j < 2; ++j) {
        *(uint4*)&KsB [srow[j] * 64 + ssw[j]] = kreg[j];
        *(uint4*)&VtsB[srow[j] * 64 + ssw[j]] = vreg[j];
    }
    __syncthreads();

    f32x16 oa0, oa1;
#pragma unroll
    for (int r = 0; r < 16; ++r) { oa0[r] = 0.f; oa1[r] = 0.f; }
    float m = -3.0e38f, lsum = 0.f;

    for (int kt = 0; kt < NT; ++kt) {
        const ushort* Ks  = &KsB [(kt & 1) * 4096];
        const ushort* Vts = &VtsB[(kt & 1) * 4096];
        ushort* Ksn  = &KsB [((kt + 1) & 1) * 4096];
        ushort* Vtsn = &VtsB[((kt + 1) & 1) * 4096];

        // T14: issue next tile's global loads first (latency hides under compute)
        if (kt + 1 < NT) {
#pragma unroll
            for (int j = 0; j < 2; ++j) {
                kreg[j] = *(const uint4*)&Kg[((size_t)(kt + 1) * 64 + srow[j]) * HD + scol[j]];
                vreg[j] = *(const uint4*)&Vg[(size_t)srow[j] * SEQ + (kt + 1) * 64 + scol[j]];
            }
        }

        // ---- QK^T: two independent chains, interleaved ----
        f32x16 sc0, sc1;
#pragma unroll
        for (int r = 0; r < 16; ++r) { sc0[r] = 0.f; sc1[r] = 0.f; }
        const int ksw0 = (lq & 7) << 3;    // rows lq and 32+lq share (row&7)
        __builtin_amdgcn_s_setprio(1);
#pragma unroll
        for (int dk = 0; dk < 4; ++dk) {
            const int col = (dk * 16 + hi * 8) ^ ksw0;
            const short8 kf0 = *(const short8*)&Ks[lq * 64 + col];
            const short8 kf1 = *(const short8*)&Ks[(32 + lq) * 64 + col];
            sc0 = __builtin_amdgcn_mfma_f32_32x32x16_bf16(kf0, qf[dk], sc0, 0, 0, 0);
            sc1 = __builtin_amdgcn_mfma_f32_32x32x16_bf16(kf1, qf[dk], sc1, 0, 0, 0);
        }
        __builtin_amdgcn_s_setprio(0);

        // ---- softmax over all 32 scores ----
        float t0 = fmaxf(fmaxf(sc0[0], sc0[1]), fmaxf(sc0[2], sc0[3]));
        float t1 = fmaxf(fmaxf(sc0[4], sc0[5]), fmaxf(sc0[6], sc0[7]));
        float t2 = fmaxf(fmaxf(sc0[8], sc0[9]), fmaxf(sc0[10], sc0[11]));
        float t3 = fmaxf(fmaxf(sc0[12], sc0[13]), fmaxf(sc0[14], sc0[15]));
        float u0 = fmaxf(fmaxf(sc1[0], sc1[1]), fmaxf(sc1[2], sc1[3]));
        float u1 = fmaxf(fmaxf(sc1[4], sc1[5]), fmaxf(sc1[6], sc1[7]));
        float u2 = fmaxf(fmaxf(sc1[8], sc1[9]), fmaxf(sc1[10], sc1[11]));
        float u3 = fmaxf(fmaxf(sc1[12], sc1[13]), fmaxf(sc1[14], sc1[15]));
        float pm = fmaxf(fmaxf(fmaxf(t0, t1), fmaxf(t2, t3)),
                         fmaxf(fmaxf(u0, u1), fmaxf(u2, u3)));
        pm = fmaxf(pm, __shfl_xor(pm, 32));

        if (!__all(pm - m <= 8.0f)) {      // T13 defer-max
            const float mn = fmaxf(m, pm);
            const float corr = __expf(m - mn);
            m = mn; lsum *= corr;
#pragma unroll
            for (int r = 0; r < 16; ++r) { oa0[r] *= corr; oa1[r] *= corr; }
        }

        float p0[16], p1[16];
#pragma unroll
        for (int r = 0; r < 16; ++r) { p0[r] = __expf(sc0[r] - m); p1[r] = __expf(sc1[r] - m); }
        lsum += (((p0[0] + p0[1]) + (p0[2] + p0[3])) + ((p0[4] + p0[5]) + (p0[6] + p0[7])))
              + (((p0[8] + p0[9]) + (p0[10] + p0[11])) + ((p0[12] + p0[13]) + (p0[14] + p0[15])))
              + (((p1[0] + p1[1]) + (p1[2] + p1[3])) + ((p1[4] + p1[5]) + (p1[6] + p1[7])))
              + (((p1[8] + p1[9]) + (p1[10] + p1[11])) + ((p1[12] + p1[13]) + (p1[14] + p1[15])));

        // ---- pack P -> bf16, exchange halves across lane^32 ----
        uint32_t pk0[8], pk1[8], x0[8], x1[8];
#pragma unroll
        for (int i = 0; i < 8; ++i) {
            asm("v_cvt_pk_bf16_f32 %0, %1, %2" : "=v"(pk0[i]) : "v"(p0[2 * i]), "v"(p0[2 * i + 1]));
            asm("v_cvt_pk_bf16_f32 %0, %1, %2" : "=v"(pk1[i]) : "v"(p1[2 * i]), "v"(p1[2 * i + 1]));
        }
#pragma unroll
        for (int i = 0; i < 8; ++i) { x0[i] = __shfl_xor(pk0[i], 32); x1[i] = __shfl_xor(pk1[i], 32); }

        union U8 { uint32_t u[4]; short8 s; };
        U8 a0, a1, b0, b1;
        a0.u[0] = hi ? x0[2]  : pk0[0];  a0.u[1] = hi ? x0[3]  : pk0[1];
        a0.u[2] = hi ? pk0[2] : x0[0];   a0.u[3] = hi ? pk0[3] : x0[1];
        a1.u[0] = hi ? x0[6]  : pk0[4];  a1.u[1] = hi ? x0[7]  : pk0[5];
        a1.u[2] = hi ? pk0[6] : x0[4];   a1.u[3] = hi ? pk0[7] : x0[5];
        b0.u[0] = hi ? x1[2]  : pk1[0];  b0.u[1] = hi ? x1[3]  : pk1[1];
        b0.u[2] = hi ? pk1[2] : x1[0];   b0.u[3] = hi ? pk1[3] : x1[1];
        b1.u[0] = hi ? x1[6]  : pk1[4];  b1.u[1] = hi ? x1[7]  : pk1[5];
        b1.u[2] = hi ? pk1[6] : x1[4];   b1.u[3] = hi ? pk1[7] : x1[5];
        const short8 pf00 = a0.s, pf01 = a1.s, pf10 = b0.s, pf11 = b1.s;

        // ---- PV: two accumulator chains, interleaved ----
        const int d0 = lq, d1 = 32 + lq;
        const int vsw0 = (d0 & 7) << 3;    // == vsw1
        const int tA = hi * 8;
        const short8 vA0 = *(const short8*)&Vts[d0 * 64 + ((tA)      ^ vsw0)];
        const short8 vA1 = *(const short8*)&Vts[d1 * 64 + ((tA)      ^ vsw0)];
        const short8 vB0 = *(const short8*)&Vts[d0 * 64 + ((tA + 16) ^ vsw0)];
        const short8 vB1 = *(const short8*)&Vts[d1 * 64 + ((tA + 16) ^ vsw0)];
        const short8 wA0 = *(const short8*)&Vts[d0 * 64 + ((tA + 32) ^ vsw0)];
        const short8 wA1 = *(const short8*)&Vts[d1 * 64 + ((tA + 32) ^ vsw0)];
        const short8 wB0 = *(const short8*)&Vts[d0 * 64 + ((tA + 48) ^ vsw0)];
        const short8 wB1 = *(const short8*)&Vts[d1 * 64 + ((tA + 48) ^ vsw0)];
        __builtin_amdgcn_s_setprio(1);
        oa0 = __builtin_amdgcn_mfma_f32_32x32x16_bf16(vA0, pf00, oa0, 0, 0, 0);
        oa1 = __builtin_amdgcn_mfma_f32_32x32x16_bf16(vA1, pf00, oa1, 0, 0, 0);
        oa0 = __builtin_amdgcn_mfma_f32_32x32x16_bf16(vB0, pf01, oa0, 0, 0, 0);
        oa1 = __builtin_amdgcn_mfma_f32_32x32x16_bf16(vB1, pf01, oa1, 0, 0, 0);
        oa0 = __builtin_amdgcn_mfma_f32_32x32x16_bf16(wA0, pf10, oa0, 0, 0, 0);
        oa1 = __builtin_amdgcn_mfma_f32_32x32x16_bf16(wA1, pf10, oa1, 0, 0, 0);
        oa0 = __builtin_amdgcn_mfma_f32_32x32x16_bf16(wB0, pf11, oa0, 0, 0, 0);
        oa1 = __builtin_amdgcn_mfma_f32_32x32x16_bf16(wB1, pf11, oa1, 0, 0, 0);
        __builtin_amdgcn_s_setprio(0);

        // ---- write prefetched tile -> other buffer; single barrier ----
        if (kt + 1 < NT) {
#pragma unroll
            for (int j = 0; j < 2; ++j) {
                *(uint4*)&Ksn [srow[j] * 64 + ssw[j]] = kreg[j];
                *(uint4*)&Vtsn[srow[j] * 64 + ssw[j]] = vreg[j];
            }
        }
        __syncthreads();
    }

    // ---- epilogue: final sum exchange, normalize, LDS transpose, store ----
    lsum += __shfl_xor(lsum, 32);
    const float inv = 1.f / lsum;

    ushort* Ow = KsB + w * 2048;           // per-wave 32x64 region (K bufs done)
#pragma unroll
    for (int r = 0; r < 16; ++r) {
        const int dd = (r & 3) + 8 * (r >> 2) + 4 * hi;
        const int swq = (lq & 7) << 3;
        Ow[lq * 64 + ((dd)      ^ swq)] = bf16rne(oa0[r] * inv);
        Ow[lq * 64 + ((dd + 32) ^ swq)] = bf16rne(oa1[r] * inv);
    }
    const size_t orow0 = (size_t)b * SEQ + (size_t)qt * 128 + w * 32;
#pragma unroll
    for (int i = 0; i < 4; ++i) {
        const int row = (l >> 3) + 8 * i;
        const int d0 = (l & 7) * 8;
        const uint4 v = *(const uint4*)&Ow[row * 64 + (d0 ^ ((row & 7) << 3))];
        *(uint4*)&Aout[(orow0 + row) * D_MODEL + h * HD + d0] = v;
    }
}

// ---------------------------------------------------------------------------
extern "C" void kernel_launch(void* const* d_in, const int* in_sizes, int n_in,
                              void* d_out, int out_size, void* d_ws, size_t ws_size,
                              hipStream_t stream) {
    const float* x  = (const float*)d_in[0];
    const float* Wq = (const float*)d_in[1];
    const float* bq = (const float*)d_in[2];
    const float* Wk = (const float*)d_in[3];
    const float* bk = (const float*)d_in[4];
    const float* Wv = (const float*)d_in[5];
    const float* bv = (const float*)d_in[6];
    const float* Wo = (const float*)d_in[7];
    const float* bo = (const float*)d_in[8];
    float* out = (float*)d_out;

    ushort* xb   = (ushort*)d_ws;
    ushort* Wqkv = xb   + (size_t)BSROWS * D_MODEL;
    ushort* Wob  = Wqkv + (size_t)3 * D_MODEL * D_MODEL;
    ushort* Qw   = Wob  + (size_t)D_MODEL * D_MODEL;
    ushort* Kw   = Qw   + (size_t)BSROWS * D_MODEL;
    ushort* Vw   = Kw   + (size_t)BSROWS * D_MODEL;
    ushort* Ab   = Vw   + (size_t)BSROWS * D_MODEL;

    convert_w<<<dim3(512, 4), 256, 0, stream>>>(Wq, Wk, Wv, Wo, Wqkv, Wob);
    convert_x<<<dim3(2048), 256, 0, stream>>>(x, xb);

    gemm_mfma<128, 0><<<dim3(32, 24), 256, 0, stream>>>(
        xb, Wqkv, bq, bk, bv, Qw, Kw, Vw);

    attn_mfma3<<<dim3(SEQ / 128, NH, NB), 256, 0, stream>>>(Qw, Kw, Vw, Ab);

    gemm_mfma<64, 1><<<dim3(32, 16), 256, 0, stream>>>(
        Ab, Wob, bo, nullptr, nullptr, out, nullptr, nullptr);
}